// Round 2
// baseline (1870.915 us; speedup 1.0000x reference)
//
#include <hip/hip_runtime.h>
#include <math.h>

// RNN: h_t = tanh(x[b,t]*W_ih + b_ih + b_hh + h_{t-1} @ W_hh^T), out = h_T @ W_out^T + b_out
// B=256 T=2048 H=256 P=24, fp32. One WG per batch (256 WGs = 256 CUs).
//
// Round-2 redesign: round-1 was LDS-broadcast-bound (256 ds_read_b128/WG/step
// ~2048 cyc vs 512 cyc FMA floor). Now each thread owns R=4 outputs over a
// C=32-wide K-chunk: same 128 FMAs/thread but only 8 ds_read_b128/thread/step
// (64/WG). K is split 8 ways; partials reduced via 3-round shfl_xor butterfly
// within each 8-lane group (no LDS traffic, no extra barrier).
//
// Bank conflicts: chunk c reads float4s in rotated order (j+c)&7, so each
// ds_read_b128 touches bank groups ((j+c)&7)*4 — distinct per c, 8-lane
// same-address broadcast within a group => conflict-free. Weights are loaded
// pre-rotated to match.

#define BB 256
#define TT 2048
#define HH 256
#define PP 24

__global__ __launch_bounds__(512, 2)
void rnn_persist(const float* __restrict__ x,
                 const float* __restrict__ W_ih,
                 const float* __restrict__ W_hh,
                 const float* __restrict__ b_ih,
                 const float* __restrict__ b_hh,
                 const float* __restrict__ W_out,
                 const float* __restrict__ b_out,
                 float* __restrict__ out)
{
    __shared__ float lds_x[TT];
    __shared__ __align__(16) float h0[HH];
    __shared__ __align__(16) float h1[HH];

    const int tid = threadIdx.x;
    const int b   = blockIdx.x;
    const int c   = tid & 7;    // K-chunk index (8 chunks of 32)
    const int g   = tid >> 3;   // output group (4 outputs: 4g..4g+3)

    // Stage this batch's x sequence (8 KB), coalesced.
    for (int i = tid; i < TT; i += 512) lds_x[i] = x[b * TT + i];
    if (tid < HH) h0[tid] = 0.0f;   // h_0 = 0

    // Weights: thread holds W_hh[4g+r, c*32 .. c*32+31] for r=0..3, stored as
    // float4s in the rotated order used by the inner loop. 128 VGPRs.
    float4 w4[4][8];
    #pragma unroll
    for (int r = 0; r < 4; ++r) {
        const float* row = W_hh + (4 * g + r) * HH;
        #pragma unroll
        for (int j = 0; j < 8; ++j) {
            const int kb = c * 32 + (((j + c) & 7) << 2);
            w4[r][j] = *(const float4*)(row + kb);
        }
    }

    // Per-thread head constants for the output this lane finalizes (c<4 only).
    const int   osel = 4 * g + (c & 3);
    const float wih  = W_ih[osel];
    const float cb   = b_ih[osel] + b_hh[osel];

    __syncthreads();

    for (int t = 0; t < TT; ++t) {
        const float* cur = (t & 1) ? h1 : h0;
        float*       nxt = (t & 1) ? h0 : h1;
        const float4* h4p = (const float4*)cur + c * 8;

        float a0 = 0.f, a1 = 0.f, a2 = 0.f, a3 = 0.f;  // 4 independent chains
        #pragma unroll
        for (int j = 0; j < 8; ++j) {
            const float4 h4 = h4p[(j + c) & 7];
            a0 = fmaf(w4[0][j].x, h4.x, a0);
            a0 = fmaf(w4[0][j].y, h4.y, a0);
            a0 = fmaf(w4[0][j].z, h4.z, a0);
            a0 = fmaf(w4[0][j].w, h4.w, a0);
            a1 = fmaf(w4[1][j].x, h4.x, a1);
            a1 = fmaf(w4[1][j].y, h4.y, a1);
            a1 = fmaf(w4[1][j].z, h4.z, a1);
            a1 = fmaf(w4[1][j].w, h4.w, a1);
            a2 = fmaf(w4[2][j].x, h4.x, a2);
            a2 = fmaf(w4[2][j].y, h4.y, a2);
            a2 = fmaf(w4[2][j].z, h4.z, a2);
            a2 = fmaf(w4[2][j].w, h4.w, a2);
            a3 = fmaf(w4[3][j].x, h4.x, a3);
            a3 = fmaf(w4[3][j].y, h4.y, a3);
            a3 = fmaf(w4[3][j].z, h4.z, a3);
            a3 = fmaf(w4[3][j].w, h4.w, a3);
        }

        // Butterfly sum across the 8 chunks (lanes g*8 .. g*8+7).
        #pragma unroll
        for (int m = 1; m <= 4; m <<= 1) {
            a0 += __shfl_xor(a0, m, 64);
            a1 += __shfl_xor(a1, m, 64);
            a2 += __shfl_xor(a2, m, 64);
            a3 += __shfl_xor(a3, m, 64);
        }

        // Lanes c=0..3 finalize output 4g+c.
        if (c < 4) {
            const float s  = (c == 0) ? a0 : (c == 1) ? a1 : (c == 2) ? a2 : a3;
            const float xt = lds_x[t];
            nxt[4 * g + c] = tanhf(fmaf(xt, wih, cb) + s);
        }
        __syncthreads();   // nxt visible; everyone done reading cur
    }

    // Head: out[b,p] = b_out[p] + W_out[p,:] . h_T  (h_T ends in h0: t=2047 odd)
    if (tid < PP) {
        const float* wo = W_out + tid * HH;
        float s0 = 0.f, s1 = 0.f, s2 = 0.f, s3 = 0.f;
        #pragma unroll
        for (int h = 0; h < HH; h += 4) {
            s0 = fmaf(wo[h + 0], h0[h + 0], s0);
            s1 = fmaf(wo[h + 1], h0[h + 1], s1);
            s2 = fmaf(wo[h + 2], h0[h + 2], s2);
            s3 = fmaf(wo[h + 3], h0[h + 3], s3);
        }
        out[b * PP + tid] = b_out[tid] + (s0 + s1) + (s2 + s3);
    }
}

extern "C" void kernel_launch(void* const* d_in, const int* in_sizes, int n_in,
                              void* d_out, int out_size, void* d_ws, size_t ws_size,
                              hipStream_t stream) {
    const float* x     = (const float*)d_in[0];
    const float* W_ih  = (const float*)d_in[1];
    const float* W_hh  = (const float*)d_in[2];
    const float* b_ih  = (const float*)d_in[3];
    const float* b_hh  = (const float*)d_in[4];
    const float* W_out = (const float*)d_in[5];
    const float* b_out = (const float*)d_in[6];
    float* out = (float*)d_out;

    rnn_persist<<<BB, 512, 0, stream>>>(x, W_ih, W_hh, b_ih, b_hh, W_out, b_out, out);
}

// Round 3
// 1281.314 us; speedup vs baseline: 1.4602x; 1.4602x over previous
//
#include <hip/hip_runtime.h>
#include <math.h>

// RNN: h_t = tanh(x[b,t]*W_ih + b_ih + b_hh + h_{t-1} @ W_hh^T), out = h_T @ W_out^T + b_out
// B=256 T=2048 H=256 P=24, fp32. One WG per batch, 512 threads (8 waves), 1 WG/CU.
//
// Round-3: rounds 1/2 were DS-pipe-bound (uniform b128 ~8cyc billed full; shfl_xor
// = ds_bpermute ~15cyc). Register blocking R=8: thread (c=tid&15, g=tid>>4) owns
// rows 8g..8g+7 over K-chunk [16c,16c+16). Per step per thread: 4 ds_read_b128 (h)
// + 128 reg-reg FMAs + 2 ds_write_b128 (partials). Reduction via LDS b32 reads by
// 256 finalizers (no shuffles). Padding: h chunk stride 20 floats, part row stride
// 260 floats -> <=2-way bank aliasing everywhere (free).

#define BB 256
#define TT 2048
#define HH 256
#define PP 24
#define HSTR 20              // h chunk stride: 16 data + 4 pad floats
#define PS   260             // part row stride: 256 data + 4 pad floats

__device__ __forceinline__ int hidx(int k) { return (k >> 4) * HSTR + (k & 15); }

__global__ __launch_bounds__(512, 2)
void rnn_persist(const float* __restrict__ x,
                 const float* __restrict__ W_ih,
                 const float* __restrict__ W_hh,
                 const float* __restrict__ b_ih,
                 const float* __restrict__ b_hh,
                 const float* __restrict__ W_out,
                 const float* __restrict__ b_out,
                 float* __restrict__ out)
{
    __shared__ float lds_x[TT];                          // 8 KB
    __shared__ __align__(16) float hbuf[2][16 * HSTR];   // 2 x 1.25 KB
    __shared__ __align__(16) float part[16 * PS];        // 16.25 KB

    const int tid = threadIdx.x;
    const int b   = blockIdx.x;
    const int c   = tid & 15;    // K-chunk 0..15
    const int g   = tid >> 4;    // row group 0..31 (rows 8g..8g+7)

    for (int i = tid; i < TT; i += 512) lds_x[i] = x[b * TT + i];
    if (tid < HH) hbuf[0][hidx(tid)] = 0.0f;   // h_0 = 0

    // Weights: rows 8g+r, cols 16c+4j. 128 regs (VGPR or AGPR-direct, both fine).
    float4 w4[8][4];
    #pragma unroll
    for (int r = 0; r < 8; ++r) {
        const float* row = W_hh + (8 * g + r) * HH + 16 * c;
        #pragma unroll
        for (int j = 0; j < 4; ++j) w4[r][j] = *(const float4*)(row + 4 * j);
    }

    // Finalizer constants (thread tid finalizes output o = tid, tid < 256).
    float wih = 0.f, cb = 0.f;
    if (tid < HH) { wih = W_ih[tid]; cb = b_ih[tid] + b_hh[tid]; }

    __syncthreads();

    const float* hc0 = hbuf[0] + c * HSTR;
    const float* hc1 = hbuf[1] + c * HSTR;
    float* pw = part + c * PS + 8 * g;        // 16B-aligned: (260c+8g)*4

    for (int t = 0; t < TT; ++t) {
        const float4* h4p = (const float4*)((t & 1) ? hc1 : hc0);
        const float4 h0_ = h4p[0], h1_ = h4p[1], h2_ = h4p[2], h3_ = h4p[3];

        float aa[8];
        #pragma unroll
        for (int r = 0; r < 8; ++r) {
            float s0 = w4[r][0].x * h0_.x + w4[r][0].y * h0_.y;
            s0 = fmaf(w4[r][0].z, h0_.z, s0); s0 = fmaf(w4[r][0].w, h0_.w, s0);
            float s1 = w4[r][1].x * h1_.x;
            s1 = fmaf(w4[r][1].y, h1_.y, s1);
            s1 = fmaf(w4[r][1].z, h1_.z, s1); s1 = fmaf(w4[r][1].w, h1_.w, s1);
            s0 = fmaf(w4[r][2].x, h2_.x, s0); s0 = fmaf(w4[r][2].y, h2_.y, s0);
            s0 = fmaf(w4[r][2].z, h2_.z, s0); s0 = fmaf(w4[r][2].w, h2_.w, s0);
            s1 = fmaf(w4[r][3].x, h3_.x, s1); s1 = fmaf(w4[r][3].y, h3_.y, s1);
            s1 = fmaf(w4[r][3].z, h3_.z, s1); s1 = fmaf(w4[r][3].w, h3_.w, s1);
            aa[r] = s0 + s1;
        }
        ((float4*)pw)[0] = make_float4(aa[0], aa[1], aa[2], aa[3]);
        ((float4*)pw)[1] = make_float4(aa[4], aa[5], aa[6], aa[7]);

        __syncthreads();   // partials visible

        if (tid < HH) {
            const float* pr = part + tid;          // part[cc][tid], stride PS
            float s0 = pr[0 * PS] + pr[1 * PS];
            float s1 = pr[2 * PS] + pr[3 * PS];
            float s2 = pr[4 * PS] + pr[5 * PS];
            float s3 = pr[6 * PS] + pr[7 * PS];
            float s4 = pr[8 * PS] + pr[9 * PS];
            float s5 = pr[10 * PS] + pr[11 * PS];
            float s6 = pr[12 * PS] + pr[13 * PS];
            float s7 = pr[14 * PS] + pr[15 * PS];
            float s = ((s0 + s1) + (s2 + s3)) + ((s4 + s5) + (s6 + s7));
            float u = fmaf(lds_x[t], wih, cb) + s;
            u = fminf(fmaxf(u, -15.f), 15.f);      // tanh(+-15)=+-1 to 1e-13
            const float e = __expf(2.f * u);
            const float th = (e - 1.f) * __builtin_amdgcn_rcpf(e + 1.f);
            hbuf[(t + 1) & 1][hidx(tid)] = th;
        }
        __syncthreads();   // h_{t+1} visible
    }

    // Head: h_T is in hbuf[0] (TT even). out[b,p] = b_out[p] + W_out[p,:].h_T
    if (tid < PP) {
        const float* wo = W_out + tid * HH;
        float s0 = 0.f, s1 = 0.f, s2 = 0.f, s3 = 0.f;
        #pragma unroll
        for (int h = 0; h < HH; h += 4) {
            s0 = fmaf(wo[h + 0], hbuf[0][hidx(h + 0)], s0);
            s1 = fmaf(wo[h + 1], hbuf[0][hidx(h + 1)], s1);
            s2 = fmaf(wo[h + 2], hbuf[0][hidx(h + 2)], s2);
            s3 = fmaf(wo[h + 3], hbuf[0][hidx(h + 3)], s3);
        }
        out[b * PP + tid] = b_out[tid] + (s0 + s1) + (s2 + s3);
    }
}

extern "C" void kernel_launch(void* const* d_in, const int* in_sizes, int n_in,
                              void* d_out, int out_size, void* d_ws, size_t ws_size,
                              hipStream_t stream) {
    const float* x     = (const float*)d_in[0];
    const float* W_ih  = (const float*)d_in[1];
    const float* W_hh  = (const float*)d_in[2];
    const float* b_ih  = (const float*)d_in[3];
    const float* b_hh  = (const float*)d_in[4];
    const float* W_out = (const float*)d_in[5];
    const float* b_out = (const float*)d_in[6];
    float* out = (float*)d_out;

    rnn_persist<<<BB, 512, 0, stream>>>(x, W_ih, W_hh, b_ih, b_hh, W_out, b_out, out);
}

// Round 4
// 1280.170 us; speedup vs baseline: 1.4615x; 1.0009x over previous
//
#include <hip/hip_runtime.h>
#include <math.h>

// RNN: h_t = tanh(x[b,t]*W_ih + b_ih + b_hh + h_{t-1} @ W_hh^T), out = h_T @ W_out^T + b_out
// B=256 T=2048 H=256 P=24, fp32. One WG/batch, 512 threads (8 waves), 1 WG/CU.
//
// Round-4: thread (c=tid&15, g=tid>>4) owns rows 8g..8g+7 over K-chunk
// [16c,16c+16). The 16 K-partials per row group live in one DPP row (lanes
// share lane&15 == c), so the reduction is 4 in-register v_add_f32_dpp
// row_ror:{1,2,4,8} per accumulator -- no LDS partials, ONE barrier/step.
// After the ror-butterfly every lane holds every row sum; lane c selects
// aa[c&7], applies tanh, lanes c<8 write h[8g+c].
// h layout padded (HSTR=20) => <=2-way bank aliasing on b128 reads (free).

#define BB 256
#define TT 2048
#define HH 256
#define PP 24
#define HSTR 20   // h chunk stride: 16 data + 4 pad floats

__device__ __forceinline__ int hidx(int k) { return (k >> 4) * HSTR + (k & 15); }

// a += rotate-within-16(a) ; rotation never leaves the row => orientation-proof
#define DPP_ROR_ADD(v, ctrl) \
    v += __int_as_float(__builtin_amdgcn_update_dpp( \
        0, __float_as_int(v), ctrl, 0xf, 0xf, true))

__global__ __launch_bounds__(512, 2)
void rnn_persist(const float* __restrict__ x,
                 const float* __restrict__ W_ih,
                 const float* __restrict__ W_hh,
                 const float* __restrict__ b_ih,
                 const float* __restrict__ b_hh,
                 const float* __restrict__ W_out,
                 const float* __restrict__ b_out,
                 float* __restrict__ out)
{
    __shared__ float lds_x[TT];                          // 8 KB
    __shared__ __align__(16) float hbuf[2][16 * HSTR];   // 2 x 1.25 KB

    const int tid = threadIdx.x;
    const int b   = blockIdx.x;
    const int c   = tid & 15;    // K-chunk 0..15 == DPP row lane
    const int g   = tid >> 4;    // row group 0..31 (rows 8g..8g+7)

    for (int i = tid; i < TT; i += 512) lds_x[i] = x[b * TT + i];
    if (tid < HH) hbuf[0][hidx(tid)] = 0.0f;   // h_0 = 0

    // Weights: rows 8g+r, cols 16c..16c+15. 128 regs.
    float4 w4[8][4];
    #pragma unroll
    for (int r = 0; r < 8; ++r) {
        const float* row = W_hh + (8 * g + r) * HH + 16 * c;
        #pragma unroll
        for (int j = 0; j < 4; ++j) w4[r][j] = *(const float4*)(row + 4 * j);
    }

    // Output this lane finalizes (only meaningful for c<8): o = 8g + (c&7)
    const int   o    = 8 * g + (c & 7);
    const float wih  = W_ih[o];
    const float cb   = b_ih[o] + b_hh[o];
    const int   widx = hidx(o);

    __syncthreads();

    const float* hc0 = hbuf[0] + c * HSTR;
    const float* hc1 = hbuf[1] + c * HSTR;

    auto step = [&](const float* __restrict__ cur, float* __restrict__ nxt,
                    int t) __attribute__((always_inline)) {
        const float4* h4p = (const float4*)cur;
        const float4 h0_ = h4p[0], h1_ = h4p[1], h2_ = h4p[2], h3_ = h4p[3];
        const float xt = lds_x[t];

        float aa[8];
        #pragma unroll
        for (int r = 0; r < 8; ++r) {
            float s0 = w4[r][0].x * h0_.x + w4[r][0].y * h0_.y;
            s0 = fmaf(w4[r][0].z, h0_.z, s0); s0 = fmaf(w4[r][0].w, h0_.w, s0);
            float s1 = w4[r][1].x * h1_.x;
            s1 = fmaf(w4[r][1].y, h1_.y, s1);
            s1 = fmaf(w4[r][1].z, h1_.z, s1); s1 = fmaf(w4[r][1].w, h1_.w, s1);
            s0 = fmaf(w4[r][2].x, h2_.x, s0); s0 = fmaf(w4[r][2].y, h2_.y, s0);
            s0 = fmaf(w4[r][2].z, h2_.z, s0); s0 = fmaf(w4[r][2].w, h2_.w, s0);
            s1 = fmaf(w4[r][3].x, h3_.x, s1); s1 = fmaf(w4[r][3].y, h3_.y, s1);
            s1 = fmaf(w4[r][3].z, h3_.z, s1); s1 = fmaf(w4[r][3].w, h3_.w, s1);
            aa[r] = s0 + s1;
        }

        // ror-butterfly: after 4 rounds every lane holds the full 16-chunk sum
        #pragma unroll
        for (int r = 0; r < 8; ++r) {
            DPP_ROR_ADD(aa[r], 0x121);   // row_ror:1
            DPP_ROR_ADD(aa[r], 0x122);   // row_ror:2
            DPP_ROR_ADD(aa[r], 0x124);   // row_ror:4
            DPP_ROR_ADD(aa[r], 0x128);   // row_ror:8
        }

        // lane c picks its row's sum (loop-invariant masks -> 7 cndmask)
        float b0 = (c & 1) ? aa[1] : aa[0];
        float b1 = (c & 1) ? aa[3] : aa[2];
        float b2 = (c & 1) ? aa[5] : aa[4];
        float b3 = (c & 1) ? aa[7] : aa[6];
        float c0 = (c & 2) ? b1 : b0;
        float c1 = (c & 2) ? b3 : b2;
        float s  = (c & 4) ? c1 : c0;

        float u = fmaf(xt, wih, cb) + s;
        u = fminf(fmaxf(u, -15.f), 15.f);
        const float e  = __expf(2.f * u);
        const float th = (e - 1.f) * __builtin_amdgcn_rcpf(e + 1.f);
        if (c < 8) nxt[widx] = th;
        __syncthreads();
    };

    for (int t = 0; t < TT; t += 2) {
        step(hc0, hbuf[1], t);
        step(hc1, hbuf[0], t + 1);
    }

    // Head: h_T in hbuf[0] (TT even). out[b,p] = b_out[p] + W_out[p,:].h_T
    if (tid < PP) {
        const float* wo = W_out + tid * HH;
        float s0 = 0.f, s1 = 0.f, s2 = 0.f, s3 = 0.f;
        #pragma unroll
        for (int h = 0; h < HH; h += 4) {
            s0 = fmaf(wo[h + 0], hbuf[0][hidx(h + 0)], s0);
            s1 = fmaf(wo[h + 1], hbuf[0][hidx(h + 1)], s1);
            s2 = fmaf(wo[h + 2], hbuf[0][hidx(h + 2)], s2);
            s3 = fmaf(wo[h + 3], hbuf[0][hidx(h + 3)], s3);
        }
        out[b * PP + tid] = b_out[tid] + (s0 + s1) + (s2 + s3);
    }
}

extern "C" void kernel_launch(void* const* d_in, const int* in_sizes, int n_in,
                              void* d_out, int out_size, void* d_ws, size_t ws_size,
                              hipStream_t stream) {
    const float* x     = (const float*)d_in[0];
    const float* W_ih  = (const float*)d_in[1];
    const float* W_hh  = (const float*)d_in[2];
    const float* b_ih  = (const float*)d_in[3];
    const float* b_hh  = (const float*)d_in[4];
    const float* W_out = (const float*)d_in[5];
    const float* b_out = (const float*)d_in[6];
    float* out = (float*)d_out;

    rnn_persist<<<BB, 512, 0, stream>>>(x, W_ih, W_hh, b_ih, b_hh, W_out, b_out, out);
}

// Round 5
// 1156.037 us; speedup vs baseline: 1.6184x; 1.1074x over previous
//
#include <hip/hip_runtime.h>
#include <math.h>

// RNN: h_t = tanh(x[b,t]*W_ih + b_ih + b_hh + h_{t-1} @ W_hh^T), out = h_T @ W_out^T + b_out
// B=256 T=2048 H=256 P=24, fp32. One WG/batch (256 WGs = 256 CUs), 512 thr, 8 waves.
//
// Round-5: R4 hit a VALU-issue wall (VALUBusy ~105%). Two fp32-exact cuts:
//  (a) v_pk_fma_f32 via float2 ext-vectors: matvec 136 -> 72 issue slots.
//  (b) tree DPP reduction (value-merging butterfly xor8/xor7/xor2/xor1):
//      39 -> 22 instrs, and even lane c directly finalizes row 8g + c/2.
// Thread (c=tid&15, g=tid>>4) owns rows 8g..8g+7 over K-chunk [16c,16c+16).
// One barrier/step. h padded (HSTR=20) => <=2-way LDS bank aliasing (free).

#define BB 256
#define TT 2048
#define HH 256
#define PP 24
#define HSTR 20   // h chunk stride: 16 data + 4 pad floats

typedef float v2f __attribute__((ext_vector_type(2)));

__device__ __forceinline__ int hidx(int k) { return (k >> 4) * HSTR + (k & 15); }

template<int CTRL>
__device__ __forceinline__ float dppadd(float dst, float src) {
    return dst + __int_as_float(__builtin_amdgcn_update_dpp(
        0, __float_as_int(src), CTRL, 0xf, 0xf, true));
}

__global__ __launch_bounds__(512, 2)
void rnn_persist(const float* __restrict__ x,
                 const float* __restrict__ W_ih,
                 const float* __restrict__ W_hh,
                 const float* __restrict__ b_ih,
                 const float* __restrict__ b_hh,
                 const float* __restrict__ W_out,
                 const float* __restrict__ b_out,
                 float* __restrict__ out)
{
    __shared__ float lds_x[TT];                          // 8 KB
    __shared__ __align__(16) float hbuf[2][16 * HSTR];   // 2 x 1.25 KB

    const int tid = threadIdx.x;
    const int b   = blockIdx.x;
    const int c   = tid & 15;    // K-chunk 0..15 (DPP row lane)
    const int g   = tid >> 4;    // row group (rows 8g..8g+7)

    for (int i = tid; i < TT; i += 512) lds_x[i] = x[b * TT + i];
    if (tid < HH) hbuf[0][hidx(tid)] = 0.0f;   // h_0 = 0

    // Weights as float2 pairs: w2[r][j] = W_hh[8g+r, 16c+2j .. 16c+2j+1]. 128 regs.
    v2f w2[8][8];
    #pragma unroll
    for (int r = 0; r < 8; ++r) {
        const float* row = W_hh + (8 * g + r) * HH + 16 * c;
        #pragma unroll
        for (int j = 0; j < 4; ++j) {
            const float4 q = *(const float4*)(row + 4 * j);
            w2[r][2 * j + 0] = (v2f){q.x, q.y};
            w2[r][2 * j + 1] = (v2f){q.z, q.w};
        }
    }

    // Reduction side predicates and the output this lane finalizes.
    const bool p1 = (c & 8) != 0, p2 = (c & 4) != 0, p3 = (c & 2) != 0;
    const int  o_fin = 8 * g + (((int)p1 << 2) | ((int)p2 << 1) | (int)p3);
    const float wih  = W_ih[o_fin];
    const float cb   = b_ih[o_fin] + b_hh[o_fin];
    const int   widx = hidx(o_fin);
    const bool  writer = (c & 1) == 0;

    __syncthreads();

    const float* hc0 = hbuf[0] + c * HSTR;
    const float* hc1 = hbuf[1] + c * HSTR;

    auto step = [&](const float* __restrict__ cur, float* __restrict__ nxt,
                    int t) __attribute__((always_inline)) {
        const float4* h4p = (const float4*)cur;
        const float4 qa = h4p[0], qb = h4p[1], qc = h4p[2], qd = h4p[3];
        v2f h2[8];
        h2[0] = (v2f){qa.x, qa.y}; h2[1] = (v2f){qa.z, qa.w};
        h2[2] = (v2f){qb.x, qb.y}; h2[3] = (v2f){qb.z, qb.w};
        h2[4] = (v2f){qc.x, qc.y}; h2[5] = (v2f){qc.z, qc.w};
        h2[6] = (v2f){qd.x, qd.y}; h2[7] = (v2f){qd.z, qd.w};
        const float xt = lds_x[t];

        float aa[8];
        #pragma unroll
        for (int r = 0; r < 8; ++r) {
            v2f acc = w2[r][0] * h2[0];
            #pragma unroll
            for (int j = 1; j < 8; ++j)
                acc = __builtin_elementwise_fma(w2[r][j], h2[j], acc);
            aa[r] = acc.x + acc.y;
        }

        // Value-merging butterfly: 8 vals over 16 lanes -> lane's own sum.
        float bb[4];
        #pragma unroll
        for (int i = 0; i < 4; ++i) {
            const float keep = p1 ? aa[i + 4] : aa[i];
            const float send = p1 ? aa[i] : aa[i + 4];
            bb[i] = dppadd<0x128>(keep, send);            // xor8 (row_ror:8)
        }
        float cc[2];
        #pragma unroll
        for (int i = 0; i < 2; ++i) {
            const float keep = p2 ? bb[i + 2] : bb[i];
            const float send = p2 ? bb[i] : bb[i + 2];
            cc[i] = dppadd<0x141>(keep, send);            // xor7 (row_half_mirror)
        }
        float d;
        {
            const float keep = p3 ? cc[1] : cc[0];
            const float send = p3 ? cc[0] : cc[1];
            d = dppadd<0x4E>(keep, send);                 // xor2 (quad_perm 2,3,0,1)
        }
        d = dppadd<0xB1>(d, d);                           // xor1 (quad_perm 1,0,3,2)

        float u = fmaf(xt, wih, cb) + d;
        u = __builtin_amdgcn_fmed3f(u, -15.f, 15.f);
        const float e  = __expf(u + u);
        const float th = (e - 1.f) * __builtin_amdgcn_rcpf(e + 1.f);
        if (writer) nxt[widx] = th;
        __syncthreads();
    };

    for (int t = 0; t < TT; t += 2) {
        step(hc0, hbuf[1], t);
        step(hc1, hbuf[0], t + 1);
    }

    // Head: h_T in hbuf[0] (TT even). out[b,p] = b_out[p] + W_out[p,:].h_T
    if (tid < PP) {
        const float* wo = W_out + tid * HH;
        float s0 = 0.f, s1 = 0.f, s2 = 0.f, s3 = 0.f;
        #pragma unroll
        for (int h = 0; h < HH; h += 4) {
            s0 = fmaf(wo[h + 0], hbuf[0][hidx(h + 0)], s0);
            s1 = fmaf(wo[h + 1], hbuf[0][hidx(h + 1)], s1);
            s2 = fmaf(wo[h + 2], hbuf[0][hidx(h + 2)], s2);
            s3 = fmaf(wo[h + 3], hbuf[0][hidx(h + 3)], s3);
        }
        out[b * PP + tid] = b_out[tid] + (s0 + s1) + (s2 + s3);
    }
}

extern "C" void kernel_launch(void* const* d_in, const int* in_sizes, int n_in,
                              void* d_out, int out_size, void* d_ws, size_t ws_size,
                              hipStream_t stream) {
    const float* x     = (const float*)d_in[0];
    const float* W_ih  = (const float*)d_in[1];
    const float* W_hh  = (const float*)d_in[2];
    const float* b_ih  = (const float*)d_in[3];
    const float* b_hh  = (const float*)d_in[4];
    const float* W_out = (const float*)d_in[5];
    const float* b_out = (const float*)d_in[6];
    float* out = (float*)d_out;

    rnn_persist<<<BB, 512, 0, stream>>>(x, W_ih, W_hh, b_ih, b_hh, W_out, b_out, out);
}

// Round 7
// 1070.307 us; speedup vs baseline: 1.7480x; 1.0801x over previous
//
#include <hip/hip_runtime.h>

// RNN: h_t = tanh(x[b,t]*W_ih + b_ih + b_hh + h_{t-1} @ W_hh^T), out = h_T @ W_out^T + b_out
// B=256 T=2048 H=256 P=24, fp32. One WG/batch (256 WGs = 256 CUs), 512 thr, 8 waves.
//
// Round-7 (= round-6 theory, build fixed: __exp2f -> __builtin_amdgcn_exp2f).
// Select-free DPP butterfly. Thread (c=tid&15, g=tid>>4) owns 8 rows of
// group g over K-chunk [16c,16c+16), but stores row (c^m[s])>>1 in slot s with
// m={0,2,7,5,8,10,15,13}. Then the 16-lane reduction is exactly 8 fused
// v_add_f32_dpp (xor8, half_mirror, quad-perms) with ZERO cndmasks:
// at every level "keep" = first half of slots, "send" = second half, and the
// partner lane's slot holds the matching row (m[i+4]=m[i]^8, m[i+2]=m[i]^7,
// m[1]=2, row(c)=row(c^1)). Even lane c finalizes row 8g+(c>>1).
// One barrier/step. h padded (HSTR=20) => <=2-way LDS bank aliasing (free).

#define BB 256
#define TT 2048
#define HH 256
#define PP 24
#define HSTR 20   // h chunk stride: 16 data + 4 pad floats

typedef float v2f __attribute__((ext_vector_type(2)));

__device__ __forceinline__ int hidx(int k) { return (k >> 4) * HSTR + (k & 15); }

template<int CTRL>
__device__ __forceinline__ float dppadd(float dst, float src) {
    return dst + __int_as_float(__builtin_amdgcn_update_dpp(
        0, __float_as_int(src), CTRL, 0xf, 0xf, true));
}

__global__ __launch_bounds__(512, 2)
void rnn_persist(const float* __restrict__ x,
                 const float* __restrict__ W_ih,
                 const float* __restrict__ W_hh,
                 const float* __restrict__ b_ih,
                 const float* __restrict__ b_hh,
                 const float* __restrict__ W_out,
                 const float* __restrict__ b_out,
                 float* __restrict__ out)
{
    __shared__ float lds_x[TT];                          // 8 KB
    __shared__ __align__(16) float hbuf[2][16 * HSTR];   // 2 x 1.25 KB

    const int tid = threadIdx.x;
    const int b   = blockIdx.x;
    const int c   = tid & 15;    // K-chunk 0..15 (DPP row lane)
    const int g   = tid >> 4;    // row group (rows 8g..8g+7)

    for (int i = tid; i < TT; i += 512) lds_x[i] = x[b * TT + i];
    if (tid < HH) hbuf[0][hidx(tid)] = 0.0f;   // h_0 = 0

    // Slot->row permutation for the select-free butterfly.
    const int m[8] = {0, 2, 7, 5, 8, 10, 15, 13};

    // Weights: slot s holds row 8g + ((c^m[s])>>1), cols 16c..16c+15. 128 regs.
    v2f w2[8][8];
    #pragma unroll
    for (int s = 0; s < 8; ++s) {
        const int row_idx = 8 * g + ((c ^ m[s]) >> 1);
        const float* row = W_hh + row_idx * HH + 16 * c;
        #pragma unroll
        for (int j = 0; j < 4; ++j) {
            const float4 q = *(const float4*)(row + 4 * j);
            w2[s][2 * j + 0] = (v2f){q.x, q.y};
            w2[s][2 * j + 1] = (v2f){q.z, q.w};
        }
    }

    // Output this (even) lane finalizes: o = 8g + (c>>1).
    const int   o_fin = 8 * g + (c >> 1);
    const float wih   = W_ih[o_fin];
    const float cb    = b_ih[o_fin] + b_hh[o_fin];
    const int   widx  = hidx(o_fin);
    const bool  writer = (c & 1) == 0;

    __syncthreads();

    const float* hc0 = hbuf[0] + c * HSTR;
    const float* hc1 = hbuf[1] + c * HSTR;

    auto step = [&](const float* __restrict__ cur, float* __restrict__ nxt,
                    int t) __attribute__((always_inline)) {
        const float4* h4p = (const float4*)cur;
        const float4 qa = h4p[0], qb = h4p[1], qc = h4p[2], qd = h4p[3];
        v2f h2[8];
        h2[0] = (v2f){qa.x, qa.y}; h2[1] = (v2f){qa.z, qa.w};
        h2[2] = (v2f){qb.x, qb.y}; h2[3] = (v2f){qb.z, qb.w};
        h2[4] = (v2f){qc.x, qc.y}; h2[5] = (v2f){qc.z, qc.w};
        h2[6] = (v2f){qd.x, qd.y}; h2[7] = (v2f){qd.z, qd.w};
        const float xt = lds_x[t];

        float aa[8];
        #pragma unroll
        for (int s = 0; s < 8; ++s) {
            v2f acc = w2[s][0] * h2[0];
            #pragma unroll
            for (int j = 1; j < 8; ++j)
                acc = __builtin_elementwise_fma(w2[s][j], h2[j], acc);
            aa[s] = acc.x + acc.y;
        }

        // Select-free butterfly: 8 fused DPP adds, no cndmasks.
        float b0 = dppadd<0x128>(aa[0], aa[4]);   // xor8 (row_ror:8)
        float b1 = dppadd<0x128>(aa[1], aa[5]);
        float b2 = dppadd<0x128>(aa[2], aa[6]);
        float b3 = dppadd<0x128>(aa[3], aa[7]);
        float c0 = dppadd<0x141>(b0, b2);         // xor7 (row_half_mirror)
        float c1 = dppadd<0x141>(b1, b3);
        float d  = dppadd<0x4E>(c0, c1);          // xor2 (quad_perm 2,3,0,1)
        float e  = dppadd<0xB1>(d, d);            // xor1 (quad_perm 1,0,3,2)

        float u = fmaf(xt, wih, cb) + e;
        u = __builtin_amdgcn_fmed3f(u, -15.f, 15.f);
        const float p  = __builtin_amdgcn_exp2f(u * 2.8853900817779268f); // e^{2u}
        const float th = fmaf(-2.f, __builtin_amdgcn_rcpf(p + 1.f), 1.f);
        if (writer) nxt[widx] = th;
        __syncthreads();
    };

    for (int t = 0; t < TT; t += 2) {
        step(hc0, hbuf[1], t);
        step(hc1, hbuf[0], t + 1);
    }

    // Head: h_T in hbuf[0] (TT even). out[b,p] = b_out[p] + W_out[p,:].h_T
    if (tid < PP) {
        const float* wo = W_out + tid * HH;
        float s0 = 0.f, s1 = 0.f, s2 = 0.f, s3 = 0.f;
        #pragma unroll
        for (int h = 0; h < HH; h += 4) {
            s0 = fmaf(wo[h + 0], hbuf[0][hidx(h + 0)], s0);
            s1 = fmaf(wo[h + 1], hbuf[0][hidx(h + 1)], s1);
            s2 = fmaf(wo[h + 2], hbuf[0][hidx(h + 2)], s2);
            s3 = fmaf(wo[h + 3], hbuf[0][hidx(h + 3)], s3);
        }
        out[b * PP + tid] = b_out[tid] + (s0 + s1) + (s2 + s3);
    }
}

extern "C" void kernel_launch(void* const* d_in, const int* in_sizes, int n_in,
                              void* d_out, int out_size, void* d_ws, size_t ws_size,
                              hipStream_t stream) {
    const float* x     = (const float*)d_in[0];
    const float* W_ih  = (const float*)d_in[1];
    const float* W_hh  = (const float*)d_in[2];
    const float* b_ih  = (const float*)d_in[3];
    const float* b_hh  = (const float*)d_in[4];
    const float* W_out = (const float*)d_in[5];
    const float* b_out = (const float*)d_in[6];
    float* out = (float*)d_out;

    rnn_persist<<<BB, 512, 0, stream>>>(x, W_ih, W_hh, b_ih, b_hh, W_out, b_out, out);
}

// Round 8
// 1041.057 us; speedup vs baseline: 1.7971x; 1.0281x over previous
//
#include <hip/hip_runtime.h>

// RNN: h_t = tanh(x[b,t]*W_ih + b_ih + b_hh + h_{t-1} @ W_hh^T), out = h_T @ W_out^T + b_out
// B=256 T=2048 H=256 P=24, fp32. One WG/batch (256 WGs = 256 CUs), 512 thr, 8 waves.
//
// Round-8: R7 + DS-decrowding. x is read via uniform scalar loads (s_load, SMEM
// pipe) instead of LDS; fmed3 clamp dropped (exp2 inf/0 saturate th to +-1
// correctly); 4-step unroll with x loads hoisted.
// Core (from R7): select-free DPP butterfly. Thread (c=tid&15, g=tid>>4) owns
// 8 rows of group g over K-chunk [16c,16c+16), storing row (c^m[s])>>1 in slot
// s, m={0,2,7,5,8,10,15,13}. Reduction = exactly 8 fused v_add_f32_dpp
// (xor8 via row_ror:8, xor7 via half_mirror, quad_perm 0x4E/0xB1), zero
// cndmasks. Even lane c finalizes row 8g+(c>>1). One barrier/step.
// h padded (HSTR=20) => <=2-way LDS bank aliasing (free per m136).

#define BB 256
#define TT 2048
#define HH 256
#define PP 24
#define HSTR 20   // h chunk stride: 16 data + 4 pad floats

typedef float v2f __attribute__((ext_vector_type(2)));

__device__ __forceinline__ int hidx(int k) { return (k >> 4) * HSTR + (k & 15); }

template<int CTRL>
__device__ __forceinline__ float dppadd(float dst, float src) {
    return dst + __int_as_float(__builtin_amdgcn_update_dpp(
        0, __float_as_int(src), CTRL, 0xf, 0xf, true));
}

__global__ __launch_bounds__(512, 2)
void rnn_persist(const float* __restrict__ x,
                 const float* __restrict__ W_ih,
                 const float* __restrict__ W_hh,
                 const float* __restrict__ b_ih,
                 const float* __restrict__ b_hh,
                 const float* __restrict__ W_out,
                 const float* __restrict__ b_out,
                 float* __restrict__ out)
{
    __shared__ __align__(16) float hbuf[2][16 * HSTR];   // 2 x 1.25 KB

    const int tid = threadIdx.x;
    const int b   = blockIdx.x;
    const int c   = tid & 15;    // K-chunk 0..15 (DPP row lane)
    const int g   = tid >> 4;    // row group (rows 8g..8g+7)

    if (tid < HH) hbuf[0][hidx(tid)] = 0.0f;   // h_0 = 0

    // Slot->row permutation for the select-free butterfly.
    const int m[8] = {0, 2, 7, 5, 8, 10, 15, 13};

    // Weights: slot s holds row 8g + ((c^m[s])>>1), cols 16c..16c+15. 128 regs.
    v2f w2[8][8];
    #pragma unroll
    for (int s = 0; s < 8; ++s) {
        const int row_idx = 8 * g + ((c ^ m[s]) >> 1);
        const float* row = W_hh + row_idx * HH + 16 * c;
        #pragma unroll
        for (int j = 0; j < 4; ++j) {
            const float4 q = *(const float4*)(row + 4 * j);
            w2[s][2 * j + 0] = (v2f){q.x, q.y};
            w2[s][2 * j + 1] = (v2f){q.z, q.w};
        }
    }

    // Output this (even) lane finalizes: o = 8g + (c>>1).
    const int   o_fin = 8 * g + (c >> 1);
    const float wih   = W_ih[o_fin];
    const float cb    = b_ih[o_fin] + b_hh[o_fin];
    const int   widx  = hidx(o_fin);
    const bool  writer = (c & 1) == 0;

    __syncthreads();

    const float* hc0 = hbuf[0] + c * HSTR;
    const float* hc1 = hbuf[1] + c * HSTR;
    const float* xb  = x + b * TT;   // uniform address stream -> s_load

    auto step = [&](const float* __restrict__ cur, float* __restrict__ nxt,
                    float xt) __attribute__((always_inline)) {
        const float4* h4p = (const float4*)cur;
        const float4 qa = h4p[0], qb = h4p[1], qc = h4p[2], qd = h4p[3];
        v2f h2[8];
        h2[0] = (v2f){qa.x, qa.y}; h2[1] = (v2f){qa.z, qa.w};
        h2[2] = (v2f){qb.x, qb.y}; h2[3] = (v2f){qb.z, qb.w};
        h2[4] = (v2f){qc.x, qc.y}; h2[5] = (v2f){qc.z, qc.w};
        h2[6] = (v2f){qd.x, qd.y}; h2[7] = (v2f){qd.z, qd.w};

        float aa[8];
        #pragma unroll
        for (int s = 0; s < 8; ++s) {
            v2f acc = w2[s][0] * h2[0];
            #pragma unroll
            for (int j = 1; j < 8; ++j)
                acc = __builtin_elementwise_fma(w2[s][j], h2[j], acc);
            aa[s] = acc.x + acc.y;
        }

        // Select-free butterfly: 8 fused DPP adds, no cndmasks.
        float b0 = dppadd<0x128>(aa[0], aa[4]);   // xor8 (row_ror:8)
        float b1 = dppadd<0x128>(aa[1], aa[5]);
        float b2 = dppadd<0x128>(aa[2], aa[6]);
        float b3 = dppadd<0x128>(aa[3], aa[7]);
        float c0 = dppadd<0x141>(b0, b2);         // xor7 (row_half_mirror)
        float c1 = dppadd<0x141>(b1, b3);
        float d  = dppadd<0x4E>(c0, c1);          // xor2 (quad_perm 2,3,0,1)
        float e  = dppadd<0xB1>(d, d);            // xor1 (quad_perm 1,0,3,2)

        // tanh(u) = 1 - 2/(e^{2u}+1); exp2 saturation gives exact +-1 at large |u|,
        // so no clamp needed (no NaN path: u is always finite).
        const float u  = fmaf(xt, wih, cb) + e;
        const float p  = __builtin_amdgcn_exp2f(u * 2.8853900817779268f); // e^{2u}
        const float th = fmaf(-2.f, __builtin_amdgcn_rcpf(p + 1.f), 1.f);
        if (writer) nxt[widx] = th;
        __syncthreads();
    };

    for (int t = 0; t < TT; t += 4) {
        const float x0 = xb[t + 0];
        const float x1 = xb[t + 1];
        const float x2 = xb[t + 2];
        const float x3 = xb[t + 3];
        step(hc0, hbuf[1], x0);
        step(hc1, hbuf[0], x1);
        step(hc0, hbuf[1], x2);
        step(hc1, hbuf[0], x3);
    }

    // Head: h_T in hbuf[0] (TT % 4 == 0). out[b,p] = b_out[p] + W_out[p,:].h_T
    if (tid < PP) {
        const float* wo = W_out + tid * HH;
        float s0 = 0.f, s1 = 0.f, s2 = 0.f, s3 = 0.f;
        #pragma unroll
        for (int h = 0; h < HH; h += 4) {
            s0 = fmaf(wo[h + 0], hbuf[0][hidx(h + 0)], s0);
            s1 = fmaf(wo[h + 1], hbuf[0][hidx(h + 1)], s1);
            s2 = fmaf(wo[h + 2], hbuf[0][hidx(h + 2)], s2);
            s3 = fmaf(wo[h + 3], hbuf[0][hidx(h + 3)], s3);
        }
        out[b * PP + tid] = b_out[tid] + (s0 + s1) + (s2 + s3);
    }
}

extern "C" void kernel_launch(void* const* d_in, const int* in_sizes, int n_in,
                              void* d_out, int out_size, void* d_ws, size_t ws_size,
                              hipStream_t stream) {
    const float* x     = (const float*)d_in[0];
    const float* W_ih  = (const float*)d_in[1];
    const float* W_hh  = (const float*)d_in[2];
    const float* b_ih  = (const float*)d_in[3];
    const float* b_hh  = (const float*)d_in[4];
    const float* W_out = (const float*)d_in[5];
    const float* b_out = (const float*)d_in[6];
    float* out = (float*)d_out;

    rnn_persist<<<BB, 512, 0, stream>>>(x, W_ih, W_hh, b_ih, b_hh, W_out, b_out, out);
}